// Round 7
// baseline (1533.930 us; speedup 1.0000x reference)
//
#include <hip/hip_runtime.h>
#include <cstdint>
#include <cstddef>

typedef unsigned short u16;
typedef short short8 __attribute__((ext_vector_type(8)));
typedef __bf16 bf16x8 __attribute__((ext_vector_type(8)));
typedef float f32x4 __attribute__((ext_vector_type(4)));

#define BB 64
#define NNODE 1024
#define EDGES 16384
#define DIM 300
#define HEADS 5
#define LAYERS 2
#define K_PAD 320
#define N_PAD 1536
#define BM 128
#define BK 32

__device__ __forceinline__ u16 f32_to_bf16(float f) {
    union { float f; uint32_t u; } v; v.f = f;
    uint32_t u = v.u;
    uint32_t r = u + 0x7fffu + ((u >> 16) & 1u);
    return (u16)(r >> 16);
}
__device__ __forceinline__ float bf16_to_f32(u16 h) {
    union { uint32_t u; float f; } v; v.u = ((uint32_t)h) << 16;
    return v.f;
}

// ---------------------------------------------------------------- CSR build
__global__ __launch_bounds__(256) void csr_build(const int* __restrict__ ei,
                                                 int* __restrict__ offs,
                                                 int* __restrict__ csr_src) {
    int b = blockIdx.x;
    const int* src = ei + (size_t)b * 2 * EDGES;
    const int* dst = src + EDGES;
    __shared__ int cnt[NNODE];
    __shared__ int grp[256];
    int t = threadIdx.x;
    for (int i = t; i < NNODE; i += 256) cnt[i] = 0;
    __syncthreads();
    for (int e = t; e < EDGES; e += 256) atomicAdd(&cnt[dst[e]], 1);
    __syncthreads();
    int c0 = cnt[4 * t + 0], c1 = cnt[4 * t + 1], c2 = cnt[4 * t + 2], c3 = cnt[4 * t + 3];
    grp[t] = c0 + c1 + c2 + c3;
    __syncthreads();
    for (int off = 1; off < 256; off <<= 1) {
        int v = (t >= off) ? grp[t - off] : 0;
        __syncthreads();
        grp[t] += v;
        __syncthreads();
    }
    int base = (t == 0) ? 0 : grp[t - 1];
    int o0 = base, o1 = o0 + c0, o2 = o1 + c1, o3 = o2 + c2;
    cnt[4 * t + 0] = o0; cnt[4 * t + 1] = o1; cnt[4 * t + 2] = o2; cnt[4 * t + 3] = o3;
    int* ob = offs + b * (NNODE + 1);
    ob[4 * t + 0] = o0; ob[4 * t + 1] = o1; ob[4 * t + 2] = o2; ob[4 * t + 3] = o3;
    if (t == 0) ob[NNODE] = EDGES;
    __syncthreads();
    for (int e = t; e < EDGES; e += 256) {
        int d = dst[e];
        int pos = atomicAdd(&cnt[d], 1);
        csr_src[(size_t)b * EDGES + pos] = src[e];
    }
}

// ------------------------------------- split W (both layers) f32 -> bf16 hi/lo, transposed
__global__ __launch_bounds__(256) void split_w_all(const float* __restrict__ W,
                                                   u16* __restrict__ hi, u16* __restrict__ lo) {
    int i = blockIdx.x * 256 + threadIdx.x;   // LAYERS*N_PAD*K_PAD exact
    int k = i % K_PAD;
    int rem = i / K_PAD;
    int n = rem % N_PAD;
    int l = rem / N_PAD;
    float v = (k < DIM && n < HEADS * DIM)
                  ? W[((size_t)l * DIM + k) * (HEADS * DIM) + n]   // transpose: Wt[n][k]
                  : 0.f;
    u16 h = f32_to_bf16(v);
    hi[i] = h;
    lo[i] = f32_to_bf16(v - bf16_to_f32(h));
}

// ------------------------------- pad+round chunk input f32 [M][300] -> bf16 [M][320]
__global__ __launch_bounds__(256) void pad_x_bf16(const float* __restrict__ X,
                                                  u16* __restrict__ Xb) {
    size_t i = (size_t)blockIdx.x * 256 + threadIdx.x;   // M*K_PAD exact
    int k = (int)(i % K_PAD);
    size_t row = i / K_PAD;
    float v = (k < DIM) ? X[row * DIM + k] : 0.f;
    Xb[i] = f32_to_bf16(v);
}

// ---------------------------------------------------------------- GEMM
// Hb[M, N_PAD](bf16) = Xb[M, K_PAD](bf16-hi) * (Whi+Wlo)[N_PAD, K_PAD]^T
__device__ __forceinline__ f32x4 mfma16(short8 a, short8 b, f32x4 c) {
    return __builtin_amdgcn_mfma_f32_16x16x32_bf16(
        __builtin_bit_cast(bf16x8, a), __builtin_bit_cast(bf16x8, b), c, 0, 0, 0);
}

__global__ __launch_bounds__(256) void gemm_bf16(const u16* __restrict__ A,
                                                 const u16* __restrict__ Bhi,
                                                 const u16* __restrict__ Blo,
                                                 u16* __restrict__ Hout) {
    __shared__ __align__(16) short lds[3][BM][BK];   // A, Bhi, Blo (16B-granule XOR swizzle)
    int t = threadIdx.x;
    int m0 = blockIdx.x * BM, n0 = blockIdx.y * BM;
    int lane = t & 63, w = t >> 6, wr = w >> 1, wc = w & 1;
    int lrow = lane & 15, kg = lane >> 4;

    const u16* gA  = A   + (size_t)m0 * K_PAD;
    const u16* gWh = Bhi + (size_t)n0 * K_PAD;
    const u16* gWl = Blo + (size_t)n0 * K_PAD;

    f32x4 acc[4][4] = {};

    for (int k0 = 0; k0 < K_PAD; k0 += BK) {
        __syncthreads();
#pragma unroll
        for (int i = 0; i < 6; i++) {
            int chunk = t + ((i & 1) << 8);       // 0..511
            int row = chunk >> 2, g = chunk & 3;
            int gsw = (g ^ ((row >> 1) & 3)) * 8;
            const u16* gs;
            short* ls;
            if (i < 2)      { gs = gA;  ls = &lds[0][row][gsw]; }
            else if (i < 4) { gs = gWh; ls = &lds[1][row][gsw]; }
            else            { gs = gWl; ls = &lds[2][row][gsw]; }
            *(short8*)ls = *(const short8*)&gs[(size_t)row * K_PAD + k0 + g * 8];
        }
        __syncthreads();

        short8 ah[4], bh[4], bl[4];
#pragma unroll
        for (int f = 0; f < 4; f++) {
            int ra = wr * 64 + f * 16 + lrow;
            int sa = (kg ^ ((ra >> 1) & 3)) * 8;
            ah[f] = *(const short8*)&lds[0][ra][sa];
            int rb = wc * 64 + f * 16 + lrow;
            int sb = (kg ^ ((rb >> 1) & 3)) * 8;
            bh[f] = *(const short8*)&lds[1][rb][sb];
            bl[f] = *(const short8*)&lds[2][rb][sb];
        }
#pragma unroll
        for (int fm = 0; fm < 4; fm++)
#pragma unroll
            for (int fn = 0; fn < 4; fn++) {
                acc[fm][fn] = mfma16(ah[fm], bl[fn], acc[fm][fn]);
                acc[fm][fn] = mfma16(ah[fm], bh[fn], acc[fm][fn]);
            }
    }

#pragma unroll
    for (int fm = 0; fm < 4; fm++)
#pragma unroll
        for (int fn = 0; fn < 4; fn++)
#pragma unroll
            for (int i = 0; i < 4; i++) {
                int row = m0 + wr * 64 + fm * 16 + (lane >> 4) * 4 + i;
                int col = n0 + wc * 64 + fn * 16 + (lane & 15);
                Hout[(size_t)row * N_PAD + col] = f32_to_bf16(acc[fm][fn][i]);
            }
}

// ------------------------------------------------- per-node head dots a_s,a_d
__global__ __launch_bounds__(256) void head_dots(const u16* __restrict__ Hb,
                                                 const float* __restrict__ att_s,
                                                 const float* __restrict__ att_d,
                                                 float* __restrict__ a_s,
                                                 float* __restrict__ a_d) {
    int node = blockIdx.x * 4 + (threadIdx.x >> 6);
    int lane = threadIdx.x & 63;
    const u16* row = Hb + (size_t)node * N_PAD;
#pragma unroll
    for (int hd = 0; hd < HEADS; hd++) {
        float ss = 0.f, sd = 0.f;
        for (int c = hd * DIM + lane; c < (hd + 1) * DIM; c += 64) {
            float hv = bf16_to_f32(row[c]);
            ss += hv * att_s[c];
            sd += hv * att_d[c];
        }
#pragma unroll
        for (int o = 32; o > 0; o >>= 1) {
            ss += __shfl_down(ss, o);
            sd += __shfl_down(sd, o);
        }
        if (lane == 0) {
            a_s[(size_t)node * HEADS + hd] = ss;
            a_d[(size_t)node * HEADS + hd] = sd;
        }
    }
}

// --------- fused scatter-softmax (online) + aggregate + bias + GELU + LayerNorm
// 320 threads = 5 waves; wave w owns head w end-to-end. No LDS in the chunk loop.
__global__ __launch_bounds__(320) void agg_kernel(const u16* __restrict__ Hb,
                                                  const float* __restrict__ a_s,
                                                  const float* __restrict__ a_d_arr,
                                                  const int* __restrict__ offs,
                                                  const int* __restrict__ csr_src,
                                                  const unsigned char* __restrict__ mask,
                                                  const float* __restrict__ bias_l,
                                                  const float* __restrict__ gamma,
                                                  const float* __restrict__ beta,
                                                  int graph0,
                                                  float* __restrict__ out_f32,
                                                  u16* __restrict__ out_bf16,
                                                  int ldo) {
    // XCD-affine swizzle: consecutive blocks of one graph stay on one XCD
    int nb = blockIdx.x;
    int xcd = nb & 7;
    int j = nb >> 3;
    int b = xcd + 8 * (j >> 10);         // local graph in [0, CB)
    int n = j & 1023;
    int node = b * NNODE + n;            // chunk-local node
    int gb = graph0 + b;                 // global graph
    int t = threadIdx.x;
    int w = t >> 6, lane = t & 63;

    __shared__ __align__(16) float s_acc[HEADS][304];
    __shared__ float s_part[2][HEADS];

    int off0 = offs[gb * (NNODE + 1) + n];
    int deg = offs[gb * (NNODE + 1) + n + 1] - off0;
    const int* slist = csr_src + (size_t)gb * EDGES + off0;

    float adh = a_d_arr[(size_t)node * HEADS + w];
    const float* as_g = a_s + (size_t)b * NNODE * HEADS;
    const unsigned char* mk_g = mask + (size_t)gb * NNODE;
    const u16* hrow0 = Hb + (size_t)b * NNODE * N_PAD + w * DIM;   // head-w base

    float m_run = -1e30f, den_run = 0.f;
    float acc0[4] = {0.f, 0.f, 0.f, 0.f};
    float acc1[4] = {0.f, 0.f, 0.f, 0.f};

    for (int c0 = 0; c0 < deg; c0 += 64) {
        int cn = min(64, deg - c0);

        // ---- score phase (lane = edge; registers only)
        int s_v = 0;
        float sc = -1e30f;
        if (lane < cn) {
            s_v = slist[c0 + lane];
            float v = as_g[s_v * HEADS + w] + adh;
            v = (v >= 0.f) ? v : 0.2f * v;
            if (mk_g[s_v]) v = -1e9f;
            sc = v;
        }
        float cm = sc;
#pragma unroll
        for (int o = 32; o > 0; o >>= 1) cm = fmaxf(cm, __shfl_xor(cm, o));
        float m_new = fmaxf(m_run, cm);
        float scale = (m_run <= -1e29f) ? 0.f : __expf(m_run - m_new);
        float p = (lane < cn) ? __expf(sc - m_new) : 0.f;
        float ds = p;
#pragma unroll
        for (int o = 32; o > 0; o >>= 1) ds += __shfl_xor(ds, o);
        den_run = den_run * scale + ds;
        m_run = m_new;
#pragma unroll
        for (int q = 0; q < 4; q++) { acc0[q] *= scale; acc1[q] *= scale; }

        // ---- gather phase: readlane broadcast (SGPR alpha + scalar-ish row base)
        uint32_t p_u = __builtin_bit_cast(uint32_t, p);
        for (int e = 0; e < cn; e++) {
            int se = __builtin_amdgcn_readlane(s_v, e);
            float a = __builtin_bit_cast(float,
                          (uint32_t)__builtin_amdgcn_readlane((int)p_u, e));
            const u16* r = hrow0 + (size_t)se * N_PAD;
            {
                unsigned long long v8 = *(const unsigned long long*)(r + 4 * lane);
                uint32_t lo = (uint32_t)v8, hi = (uint32_t)(v8 >> 32);
                acc0[0] += a * __builtin_bit_cast(float, lo << 16);
                acc0[1] += a * __builtin_bit_cast(float, lo & 0xffff0000u);
                acc0[2] += a * __builtin_bit_cast(float, hi << 16);
                acc0[3] += a * __builtin_bit_cast(float, hi & 0xffff0000u);
            }
            if (lane < 11) {
                unsigned long long v8 = *(const unsigned long long*)(r + 256 + 4 * lane);
                uint32_t lo = (uint32_t)v8, hi = (uint32_t)(v8 >> 32);
                acc1[0] += a * __builtin_bit_cast(float, lo << 16);
                acc1[1] += a * __builtin_bit_cast(float, lo & 0xffff0000u);
                acc1[2] += a * __builtin_bit_cast(float, hi << 16);
                acc1[3] += a * __builtin_bit_cast(float, hi & 0xffff0000u);
            }
        }
    }

    // ---- normalize + head-mean factor, publish per-head partials
    float inv = 0.2f / (den_run + 1e-16f);
    f32x4 st0 = { acc0[0] * inv, acc0[1] * inv, acc0[2] * inv, acc0[3] * inv };
    *(f32x4*)&s_acc[w][4 * lane] = st0;
    if (lane < 11) {
        f32x4 st1 = { acc1[0] * inv, acc1[1] * inv, acc1[2] * inv, acc1[3] * inv };
        *(f32x4*)&s_acc[w][256 + 4 * lane] = st1;
    }
    __syncthreads();

    // ---- epilogue: sum heads + bias + GELU(tanh)
    float g = 0.f;
    if (t < DIM) {
        float x = s_acc[0][t] + s_acc[1][t] + s_acc[2][t] + s_acc[3][t] + s_acc[4][t]
                  + bias_l[t];
        float u = 0.7978845608028654f * (x + 0.044715f * x * x * x);
        g = 0.5f * x * (1.f + tanhf(u));
    }
    // LayerNorm via wave shuffles + 5-partial broadcast
    float sum = g;
#pragma unroll
    for (int o = 32; o > 0; o >>= 1) sum += __shfl_xor(sum, o);
    if (lane == 0) s_part[0][w] = sum;
    __syncthreads();
    float mu = (s_part[0][0] + s_part[0][1] + s_part[0][2] + s_part[0][3] + s_part[0][4])
               * (1.f / DIM);
    float dv = (t < DIM) ? (g - mu) : 0.f;
    float sq = dv * dv;
#pragma unroll
    for (int o = 32; o > 0; o >>= 1) sq += __shfl_xor(sq, o);
    if (lane == 0) s_part[1][w] = sq;
    __syncthreads();
    float var = (s_part[1][0] + s_part[1][1] + s_part[1][2] + s_part[1][3] + s_part[1][4])
                * (1.f / DIM);
    if (out_bf16) {
        if (t < DIM) {
            float y = dv * rsqrtf(var + 1e-5f) * gamma[t] + beta[t];
            out_bf16[(size_t)node * ldo + t] = f32_to_bf16(y);
        } else {
            out_bf16[(size_t)node * ldo + t] = 0;   // zero-pad k in [300,320)
        }
    } else if (t < DIM) {
        float y = dv * rsqrtf(var + 1e-5f) * gamma[t] + beta[t];
        out_f32[(size_t)node * ldo + t] = y;
    }
}

// ---------------------------------------------------------------- launch
extern "C" void kernel_launch(void* const* d_in, const int* in_sizes, int n_in,
                              void* d_out, int out_size, void* d_ws, size_t ws_size,
                              hipStream_t stream) {
    const float* t2      = (const float*)d_in[0];
    const int*   ei      = (const int*)d_in[1];
    const unsigned char* mask = (const unsigned char*)d_in[2];
    const float* W       = (const float*)d_in[3];
    const float* att_src = (const float*)d_in[4];
    const float* att_dst = (const float*)d_in[5];
    const float* bias    = (const float*)d_in[6];
    const float* gamma   = (const float*)d_in[7];
    const float* beta    = (const float*)d_in[8];

    // ---- pick largest chunk (graphs per pass) whose workspace fits ws_size
    auto aln = [](size_t b) { return (b + 255) & ~(size_t)255; };
    auto need = [&](int CB) {
        size_t s = 0;
        s += aln((size_t)LAYERS * N_PAD * K_PAD * 2) * 2;        // W hi+lo
        s += aln((size_t)CB * NNODE * K_PAD * 2);                // Xb (bf16)
        s += aln((size_t)CB * NNODE * N_PAD * 2);                // Hb
        s += aln((size_t)CB * NNODE * HEADS * 4) * 2;            // a_s, a_d
        s += aln((size_t)BB * (NNODE + 1) * 4);                  // offs
        s += aln((size_t)BB * EDGES * 4);                        // csr
        return s;
    };
    int CB = 32;
    if (ws_size == 0) CB = 8;
    else while (CB > 8 && need(CB) > ws_size) CB >>= 1;
    const int MC = CB * NNODE;

    char* p = (char*)d_ws;
    auto alloc = [&](size_t bytes) {
        char* r = p;
        p += (bytes + 255) & ~(size_t)255;
        return r;
    };
    u16* Wthi = (u16*)alloc((size_t)LAYERS * N_PAD * K_PAD * 2);
    u16* Wtlo = (u16*)alloc((size_t)LAYERS * N_PAD * K_PAD * 2);
    u16* Xb   = (u16*)alloc((size_t)MC * K_PAD * 2);
    u16* Hb   = (u16*)alloc((size_t)MC * N_PAD * 2);
    float* a_s = (float*)alloc((size_t)MC * HEADS * 4);
    float* a_d = (float*)alloc((size_t)MC * HEADS * 4);
    int* offs  = (int*)alloc((size_t)BB * (NNODE + 1) * 4);
    int* csr   = (int*)alloc((size_t)BB * EDGES * 4);

    csr_build<<<BB, 256, 0, stream>>>(ei, offs, csr);
    split_w_all<<<(LAYERS * N_PAD * K_PAD) / 256, 256, 0, stream>>>(W, Wthi, Wtlo);

    for (int g0 = 0; g0 < BB; g0 += CB) {
        pad_x_bf16<<<(MC * K_PAD) / 256, 256, 0, stream>>>(t2 + (size_t)g0 * NNODE * DIM, Xb);
        for (int l = 0; l < LAYERS; l++) {
            dim3 gg(MC / BM, N_PAD / BM);
            gemm_bf16<<<gg, 256, 0, stream>>>(Xb,
                                              Wthi + (size_t)l * N_PAD * K_PAD,
                                              Wtlo + (size_t)l * N_PAD * K_PAD, Hb);
            head_dots<<<MC / 4, 256, 0, stream>>>(Hb, att_src + (size_t)l * HEADS * DIM,
                                                  att_dst + (size_t)l * HEADS * DIM, a_s, a_d);
            if (l == LAYERS - 1) {
                agg_kernel<<<MC, 320, 0, stream>>>(Hb, a_s, a_d, offs, csr, mask,
                                                   bias + (size_t)l * DIM, gamma, beta,
                                                   g0, (float*)d_out + (size_t)g0 * NNODE * DIM,
                                                   nullptr, DIM);
            } else {
                agg_kernel<<<MC, 320, 0, stream>>>(Hb, a_s, a_d, offs, csr, mask,
                                                   bias + (size_t)l * DIM, gamma, beta,
                                                   g0, nullptr, Xb, K_PAD);
            }
        }
    }
}